// Round 2
// baseline (365.386 us; speedup 1.0000x reference)
//
#include <hip/hip_runtime.h>
#include <hip/hip_bf16.h>

#define HD 256
#define NN 32768
#define NE 262144
#define NB 128
#define NM 512

typedef short bf16x8 __attribute__((ext_vector_type(8)));
typedef float f32x4 __attribute__((ext_vector_type(4)));
typedef unsigned short u16;
typedef unsigned short u16x8 __attribute__((ext_vector_type(8)));
typedef unsigned short u16x4 __attribute__((ext_vector_type(4)));

__device__ __forceinline__ float b2f(u16 u) {
    unsigned int i = ((unsigned int)u) << 16;
    float f; __builtin_memcpy(&f, &i, 4); return f;
}
__device__ __forceinline__ u16 f2b(float f) {
    unsigned int i; __builtin_memcpy(&i, &f, 4);
    return (u16)((i + 0x7FFFu + ((i >> 16) & 1u)) >> 16);
}

// ---------------- CSR build ----------------
__global__ __launch_bounds__(256) void k_hist(const int* __restrict__ dst, int* __restrict__ deg) {
    int e = blockIdx.x * 256 + threadIdx.x;
    if (e < NE) atomicAdd(&deg[dst[e]], 1);
}

__global__ __launch_bounds__(1024) void k_scan(const int* __restrict__ deg,
                                               int* __restrict__ offs, int* __restrict__ cur) {
    __shared__ int sums[1024];
    int t = threadIdx.x;
    int base = t * 32;
    int loc[32];
    int s = 0;
#pragma unroll
    for (int i = 0; i < 32; i++) { loc[i] = s; s += deg[base + i]; }
    sums[t] = s;
    __syncthreads();
    for (int o = 1; o < 1024; o <<= 1) {
        int v = 0;
        if (t >= o) v = sums[t - o];
        __syncthreads();
        if (t >= o) sums[t] += v;
        __syncthreads();
    }
    int pre = sums[t] - s;  // exclusive prefix of this thread's chunk
#pragma unroll
    for (int i = 0; i < 32; i++) { int v = pre + loc[i]; offs[base + i] = v; cur[base + i] = v; }
    if (t == 1023) offs[NN] = sums[1023];
}

__global__ __launch_bounds__(256) void k_fill(const int* __restrict__ src, const int* __restrict__ dst,
                                              int* __restrict__ cur, int* __restrict__ csr) {
    int e = blockIdx.x * 256 + threadIdx.x;
    if (e < NE) {
        int p = atomicAdd(&cur[dst[e]], 1);
        csr[p] = src[e];
    }
}

// ---------------- weight transpose + f32->bf16 convert ----------------
__global__ __launch_bounds__(256) void k_transpose(const float* __restrict__ W, u16* __restrict__ Wt,
                                                   int K, int N) {
    int idx = blockIdx.x * 256 + threadIdx.x;
    if (idx < K * N) {
        int k = idx / N, n = idx - k * N;
        Wt[(size_t)n * K + k] = f2b(W[idx]);
    }
}

// ---------------- input projection ----------------
// h0[n][j] = sum_k x[n,k]*Win[k,j] + Win[32+player[g],j] + b_in[j]
__global__ __launch_bounds__(256) void k_inproj(const float* __restrict__ x, const int* __restrict__ player,
                                                const float* __restrict__ Win, const float* __restrict__ bin,
                                                u16* __restrict__ h0) {
    const int j = threadIdx.x;
    const int node0 = blockIdx.x * 128;   // 128 consecutive nodes -> same graph
    const int g = node0 >> 8;
    __shared__ float xs[128 * 32];
    for (int i = j; i < 128 * 32; i += 256) xs[i] = x[(size_t)node0 * 32 + i];
    float w[32];
#pragma unroll
    for (int k = 0; k < 32; k++) w[k] = Win[k * HD + j];
    const int pl = player[g];
    const float cadd = Win[(32 + pl) * HD + j] + bin[j];
    __syncthreads();
#pragma unroll 4
    for (int i = 0; i < 128; i++) {
        float a = cadd;
#pragma unroll
        for (int k = 0; k < 32; k++) a += xs[i * 32 + k] * w[k];
        h0[(size_t)(node0 + i) * HD + j] = f2b(a);
    }
}

// ---------------- GIN aggregation: hin = h + sum_{e:dst=n} h[src_e] ----------------
__global__ __launch_bounds__(256) void k_agg(const u16* __restrict__ h, const int* __restrict__ offs,
                                             const int* __restrict__ csr, u16* __restrict__ hin) {
    const int wv = threadIdx.x >> 6, lane = threadIdx.x & 63;
    const int n = blockIdx.x * 4 + wv;
    const int o0 = offs[n], o1 = offs[n + 1];
    const int fo = lane * 4;
    u16x4 sv = *(const u16x4*)(h + (size_t)n * HD + fo);
    float a0 = b2f(sv[0]), a1 = b2f(sv[1]), a2 = b2f(sv[2]), a3 = b2f(sv[3]);
    for (int e = o0; e < o1; ++e) {
        int s = csr[e];
        u16x4 v = *(const u16x4*)(h + (size_t)s * HD + fo);
        a0 += b2f(v[0]); a1 += b2f(v[1]); a2 += b2f(v[2]); a3 += b2f(v[3]);
    }
    u16x4 o; o[0] = f2b(a0); o[1] = f2b(a1); o[2] = f2b(a2); o[3] = f2b(a3);
    *(u16x4*)(hin + (size_t)n * HD + fo) = o;
}

// ---------------- GIN GEMM + bias + LayerNorm (+residual) + ReLU ----------------
__global__ __launch_bounds__(256) void k_gin_gemm(const u16* __restrict__ hin, const u16* __restrict__ Wt,
                                                  const float* __restrict__ bias, const float* __restrict__ lng,
                                                  const float* __restrict__ lnb, const u16* __restrict__ res,
                                                  u16* __restrict__ hout) {
    const int tid = threadIdx.x;
    const int wv = tid >> 6, lane = tid & 63;
    const int l15 = lane & 15, lg = lane >> 4;
    const int row0 = blockIdx.x * 64;

    __shared__ u16 As[64][40];    // padded to 40 to break bank conflicts
    __shared__ u16 Bs[256][40];   // W^T rows: Bs[n][k]
    __shared__ float redS[4][64], redQ[4][64];
    __shared__ float mrow[64], vrow[64];
    __shared__ float biasL[256], gL[256], bL[256];

    biasL[tid] = bias[tid];
    gL[tid] = lng[tid];
    bL[tid] = lnb[tid];

    f32x4 acc[4][4];
#pragma unroll
    for (int i = 0; i < 4; i++)
#pragma unroll
        for (int j = 0; j < 4; j++) acc[i][j] = (f32x4){0.f, 0.f, 0.f, 0.f};

    const int ar = tid >> 2, asg = tid & 3;

    for (int ks = 0; ks < 8; ++ks) {
        __syncthreads();
        // stage A: 64 rows x 32 k
        *(u16x8*)&As[ar][asg * 8] =
            *(const u16x8*)&hin[(size_t)(row0 + ar) * HD + ks * 32 + asg * 8];
        // stage B^T: 256 n-rows x 32 k
        const u16x8* bsrc = (const u16x8*)&Wt[(size_t)tid * HD + ks * 32];
#pragma unroll
        for (int q = 0; q < 4; q++) *(u16x8*)&Bs[tid][q * 8] = bsrc[q];
        __syncthreads();
        bf16x8 af[4], bf[4];
#pragma unroll
        for (int fr = 0; fr < 4; fr++) af[fr] = *(const bf16x8*)&As[fr * 16 + l15][lg * 8];
#pragma unroll
        for (int fc = 0; fc < 4; fc++) bf[fc] = *(const bf16x8*)&Bs[wv * 64 + fc * 16 + l15][lg * 8];
#pragma unroll
        for (int fr = 0; fr < 4; fr++)
#pragma unroll
            for (int fc = 0; fc < 4; fc++)
                acc[fr][fc] = __builtin_amdgcn_mfma_f32_16x16x32_bf16(af[fr], bf[fc], acc[fr][fc], 0, 0, 0);
    }

    // per-wave partial row sums of z and z^2 (z includes bias)
    float ps[4][4], qs[4][4];
#pragma unroll
    for (int fr = 0; fr < 4; fr++)
#pragma unroll
        for (int e = 0; e < 4; e++) {
            float p = 0.f, q = 0.f;
#pragma unroll
            for (int fc = 0; fc < 4; fc++) {
                int c = wv * 64 + fc * 16 + l15;
                float z = acc[fr][fc][e] + biasL[c];
                p += z; q += z * z;
            }
#pragma unroll
            for (int m = 1; m < 16; m <<= 1) { p += __shfl_xor(p, m, 64); q += __shfl_xor(q, m, 64); }
            ps[fr][e] = p; qs[fr][e] = q;
        }
    __syncthreads();
    if (l15 == 0) {
#pragma unroll
        for (int fr = 0; fr < 4; fr++)
#pragma unroll
            for (int e = 0; e < 4; e++) {
                int r = fr * 16 + lg * 4 + e;
                redS[wv][r] = ps[fr][e];
                redQ[wv][r] = qs[fr][e];
            }
    }
    __syncthreads();
    if (tid < 64) {
        float s = redS[0][tid] + redS[1][tid] + redS[2][tid] + redS[3][tid];
        float q = redQ[0][tid] + redQ[1][tid] + redQ[2][tid] + redQ[3][tid];
        float m = s * (1.0f / HD);
        float var = q * (1.0f / HD) - m * m;
        mrow[tid] = m;
        vrow[tid] = rsqrtf(var + 1e-5f);
    }
    __syncthreads();
    const bool hasRes = (res != nullptr);
#pragma unroll
    for (int fr = 0; fr < 4; fr++)
#pragma unroll
        for (int fc = 0; fc < 4; fc++)
#pragma unroll
            for (int e = 0; e < 4; e++) {
                int r = fr * 16 + lg * 4 + e;
                int c = wv * 64 + fc * 16 + l15;
                float z = acc[fr][fc][e] + biasL[c];
                float y = (z - mrow[r]) * vrow[r] * gL[c] + bL[c];
                if (hasRes) y += b2f(res[(size_t)(row0 + r) * HD + c]);
                y = fmaxf(y, 0.f);
                hout[(size_t)(row0 + r) * HD + c] = f2b(y);
            }
}

// ---------------- global mean pool ----------------
__global__ __launch_bounds__(256) void k_pool(const u16* __restrict__ h, float* __restrict__ ge) {
    int g = blockIdx.x, j = threadIdx.x;
    const u16* p = h + (size_t)g * 256 * HD + j;
    float s = 0.f;
    for (int i = 0; i < 256; i++) s += b2f(p[(size_t)i * HD]);
    ge[g * HD + j] = s * (1.0f / 256.0f);
}

// ---------------- value head ----------------
__global__ __launch_bounds__(256) void k_value(const float* __restrict__ ge,
                                               const float* __restrict__ W1, const float* __restrict__ b1,
                                               const float* __restrict__ W2, const float* __restrict__ b2p,
                                               const float* __restrict__ g1, const float* __restrict__ be1,
                                               const float* __restrict__ m1, const float* __restrict__ v1,
                                               const float* __restrict__ g2, const float* __restrict__ be2,
                                               const float* __restrict__ m2, const float* __restrict__ v2,
                                               const float* __restrict__ Wv, const float* __restrict__ bv,
                                               float* __restrict__ out) {
    int g = blockIdx.x, j = threadIdx.x;
    __shared__ float buf[256];
    __shared__ float red[4];
    buf[j] = ge[g * HD + j];
    __syncthreads();
    float z = 0.f;
    for (int k = 0; k < HD; k++) z += buf[k] * W1[k * HD + j];
    z += b1[j];
    z = (z - m1[j]) * rsqrtf(v1[j] + 1e-5f) * g1[j] + be1[j];
    z = fmaxf(z, 0.f);
    __syncthreads();
    buf[j] = z;
    __syncthreads();
    float z2 = 0.f;
    for (int k = 0; k < HD; k++) z2 += buf[k] * W2[k * HD + j];
    z2 += b2p[j];
    z2 = (z2 - m2[j]) * rsqrtf(v2[j] + 1e-5f) * g2[j] + be2[j];
    z2 = fmaxf(z2, 0.f);
    float pv = z2 * Wv[j];
#pragma unroll
    for (int m = 1; m < 64; m <<= 1) pv += __shfl_xor(pv, m, 64);
    if ((j & 63) == 0) red[j >> 6] = pv;
    __syncthreads();
    if (j == 0) out[g] = tanhf(red[0] + red[1] + red[2] + red[3] + bv[0]);
}

// ---------------- policy head: gathered GEMM + relu + dot(Wp2) ----------------
__global__ __launch_bounds__(256) void k_policy(const u16* __restrict__ h, const u16* __restrict__ Wp1t,
                                                const float* __restrict__ bp1, const float* __restrict__ wp2,
                                                const float* __restrict__ bp2, const int* __restrict__ mov,
                                                float* __restrict__ out) {
    const int tid = threadIdx.x;
    const int wv = tid >> 6, lane = tid & 63;
    const int l15 = lane & 15, lg = lane >> 4;
    const int row0 = blockIdx.x * 64;

    __shared__ u16 As[64][40];
    __shared__ u16 Bs[256][40];
    __shared__ float red[4][64];
    __shared__ float bp1L[256], wp2L[256];
    __shared__ int sIdx[64], tIdx[64], vld[64];

    bp1L[tid] = bp1[tid];
    wp2L[tid] = wp2[tid];
    if (tid < 64) {
        int a = mov[(size_t)(row0 + tid) * 2 + 0];
        int b = mov[(size_t)(row0 + tid) * 2 + 1];
        vld[tid] = (a != -1) && (b != -1);
        sIdx[tid] = a < 0 ? 0 : a;
        tIdx[tid] = b < 0 ? 0 : b;
    }

    f32x4 acc[4][4];
#pragma unroll
    for (int i = 0; i < 4; i++)
#pragma unroll
        for (int j = 0; j < 4; j++) acc[i][j] = (f32x4){0.f, 0.f, 0.f, 0.f};

    const int ar = tid >> 2, asg = tid & 3;

    for (int ks = 0; ks < 16; ++ks) {
        __syncthreads();
        int node = (ks < 8) ? sIdx[ar] : tIdx[ar];
        *(u16x8*)&As[ar][asg * 8] =
            *(const u16x8*)&h[(size_t)node * HD + (ks & 7) * 32 + asg * 8];
        const u16x8* bsrc = (const u16x8*)&Wp1t[(size_t)tid * 512 + ks * 32];
#pragma unroll
        for (int q = 0; q < 4; q++) *(u16x8*)&Bs[tid][q * 8] = bsrc[q];
        __syncthreads();
        bf16x8 af[4], bf[4];
#pragma unroll
        for (int fr = 0; fr < 4; fr++) af[fr] = *(const bf16x8*)&As[fr * 16 + l15][lg * 8];
#pragma unroll
        for (int fc = 0; fc < 4; fc++) bf[fc] = *(const bf16x8*)&Bs[wv * 64 + fc * 16 + l15][lg * 8];
#pragma unroll
        for (int fr = 0; fr < 4; fr++)
#pragma unroll
            for (int fc = 0; fc < 4; fc++)
                acc[fr][fc] = __builtin_amdgcn_mfma_f32_16x16x32_bf16(af[fr], bf[fc], acc[fr][fc], 0, 0, 0);
    }

    float ps[4][4];
#pragma unroll
    for (int fr = 0; fr < 4; fr++)
#pragma unroll
        for (int e = 0; e < 4; e++) {
            float p = 0.f;
#pragma unroll
            for (int fc = 0; fc < 4; fc++) {
                int c = wv * 64 + fc * 16 + l15;
                float z = acc[fr][fc][e] + bp1L[c];
                z = fmaxf(z, 0.f);
                p += z * wp2L[c];
            }
#pragma unroll
            for (int m = 1; m < 16; m <<= 1) p += __shfl_xor(p, m, 64);
            ps[fr][e] = p;
        }
    __syncthreads();
    if (l15 == 0) {
#pragma unroll
        for (int fr = 0; fr < 4; fr++)
#pragma unroll
            for (int e = 0; e < 4; e++) red[wv][fr * 16 + lg * 4 + e] = ps[fr][e];
    }
    __syncthreads();
    if (tid < 64) {
        float v = red[0][tid] + red[1][tid] + red[2][tid] + red[3][tid] + bp2[0];
        out[row0 + tid] = vld[tid] ? v : -1e9f;
    }
}

extern "C" void kernel_launch(void* const* d_in, const int* in_sizes, int n_in,
                              void* d_out, int out_size, void* d_ws, size_t ws_size,
                              hipStream_t stream) {
    const float* x    = (const float*)d_in[0];
    const int* eidx   = (const int*)d_in[1];
    const int* mov    = (const int*)d_in[2];
    const int* player = (const int*)d_in[3];
    const float* Win  = (const float*)d_in[5];
    const float* b_in = (const float*)d_in[6];
    const float* Wg1 = (const float*)d_in[7],  *bg1 = (const float*)d_in[8];
    const float* Wg2 = (const float*)d_in[9],  *bg2 = (const float*)d_in[10];
    const float* Wg3 = (const float*)d_in[11], *bg3 = (const float*)d_in[12];
    const float* ln1g = (const float*)d_in[13], *ln1b = (const float*)d_in[14];
    const float* ln2g = (const float*)d_in[15], *ln2b = (const float*)d_in[16];
    const float* ln3g = (const float*)d_in[17], *ln3b = (const float*)d_in[18];
    const float* Wfc1 = (const float*)d_in[19], *bfc1 = (const float*)d_in[20];
    const float* Wfc2 = (const float*)d_in[21], *bfc2 = (const float*)d_in[22];
    const float* bn1g = (const float*)d_in[23], *bn1b = (const float*)d_in[24];
    const float* bn1m = (const float*)d_in[25], *bn1v = (const float*)d_in[26];
    const float* bn2g = (const float*)d_in[27], *bn2b = (const float*)d_in[28];
    const float* bn2m = (const float*)d_in[29], *bn2v = (const float*)d_in[30];
    const float* Wp1 = (const float*)d_in[31], *bp1 = (const float*)d_in[32];
    const float* Wp2 = (const float*)d_in[33], *bp2 = (const float*)d_in[34];
    const float* Wv  = (const float*)d_in[35], *bv  = (const float*)d_in[36];

    char* ws = (char*)d_ws;
    size_t off = 0;
    auto alloc = [&](size_t bytes) {
        size_t p = off;
        off = (off + bytes + 255) & ~(size_t)255;
        return (void*)(ws + p);
    };
    u16* h0   = (u16*)alloc((size_t)NN * HD * 2);
    u16* hc   = (u16*)alloc((size_t)NN * HD * 2);
    u16* hin  = (u16*)alloc((size_t)NN * HD * 2);
    u16* Wt1  = (u16*)alloc((size_t)HD * HD * 2);
    u16* Wt2  = (u16*)alloc((size_t)HD * HD * 2);
    u16* Wt3  = (u16*)alloc((size_t)HD * HD * 2);
    u16* Wp1t = (u16*)alloc((size_t)512 * HD * 2);
    int* deg  = (int*)alloc((size_t)NN * 4);
    int* offs = (int*)alloc((size_t)(NN + 1) * 4);
    int* cur  = (int*)alloc((size_t)NN * 4);
    int* csr  = (int*)alloc((size_t)NE * 4);
    float* ge = (float*)alloc((size_t)NB * HD * 4);

    const int* esrc = eidx;
    const int* edst = eidx + NE;

    hipMemsetAsync(deg, 0, (size_t)NN * 4, stream);
    k_hist<<<NE / 256, 256, 0, stream>>>(edst, deg);
    k_scan<<<1, 1024, 0, stream>>>(deg, offs, cur);
    k_fill<<<NE / 256, 256, 0, stream>>>(esrc, edst, cur, csr);

    k_transpose<<<(HD * HD + 255) / 256, 256, 0, stream>>>(Wg1, Wt1, HD, HD);
    k_transpose<<<(HD * HD + 255) / 256, 256, 0, stream>>>(Wg2, Wt2, HD, HD);
    k_transpose<<<(HD * HD + 255) / 256, 256, 0, stream>>>(Wg3, Wt3, HD, HD);
    k_transpose<<<(512 * HD + 255) / 256, 256, 0, stream>>>(Wp1, Wp1t, 512, HD);

    k_inproj<<<NN / 128, 256, 0, stream>>>(x, player, Win, b_in, h0);

    // layer 1
    k_agg<<<NN / 4, 256, 0, stream>>>(h0, offs, csr, hin);
    k_gin_gemm<<<NN / 64, 256, 0, stream>>>(hin, Wt1, bg1, ln1g, ln1b, nullptr, hc);
    // layer 2
    k_agg<<<NN / 4, 256, 0, stream>>>(hc, offs, csr, hin);
    k_gin_gemm<<<NN / 64, 256, 0, stream>>>(hin, Wt2, bg2, ln2g, ln2b, nullptr, hc);
    // layer 3 (+residual)
    k_agg<<<NN / 4, 256, 0, stream>>>(hc, offs, csr, hin);
    k_gin_gemm<<<NN / 64, 256, 0, stream>>>(hin, Wt3, bg3, ln3g, ln3b, h0, hc);

    k_pool<<<NB, 256, 0, stream>>>(hc, ge);
    k_value<<<NB, 256, 0, stream>>>(ge, Wfc1, bfc1, Wfc2, bfc2,
                                    bn1g, bn1b, bn1m, bn1v, bn2g, bn2b, bn2m, bn2v,
                                    Wv, bv, ((float*)d_out) + NB * NM);
    k_policy<<<(NB * NM) / 64, 256, 0, stream>>>(hc, Wp1t, bp1, Wp2, bp2, mov, (float*)d_out);
}